// Round 6
// baseline (180.703 us; speedup 1.0000x reference)
//
#include <hip/hip_runtime.h>

// Problem constants (from reference)
#define N_GRAPHS  4096
#define NPG       256      // nodes per graph (contiguous batch segments)
#define F_IN      16
#define HID       32
#define LOG2E     1.4426950408889634f

typedef _Float16 half8   __attribute__((ext_vector_type(8)));  // 4 VGPR MFMA A/B
typedef __fp16   fp16x2  __attribute__((ext_vector_type(2)));  // cvt_pkrtz ret type
typedef float    float4v __attribute__((ext_vector_type(4)));  // MFMA C/D

#if __has_builtin(__builtin_amdgcn_exp2f)
#define EXP2(x) __builtin_amdgcn_exp2f(x)
#else
#define EXP2(x) exp2f(x)
#endif

union AU { uint4 u; half8 h; };

// Pack 8 f32 -> 8 f16 with v_cvt_pkrtz (2 elems/inst).
__device__ __forceinline__ half8 pack8(const float f[8]) {
    half8 r;
#if __has_builtin(__builtin_amdgcn_cvt_pkrtz)
    fp16x2 p;
    p = __builtin_amdgcn_cvt_pkrtz(f[0], f[1]); r[0] = (_Float16)p.x; r[1] = (_Float16)p.y;
    p = __builtin_amdgcn_cvt_pkrtz(f[2], f[3]); r[2] = (_Float16)p.x; r[3] = (_Float16)p.y;
    p = __builtin_amdgcn_cvt_pkrtz(f[4], f[5]); r[4] = (_Float16)p.x; r[5] = (_Float16)p.y;
    p = __builtin_amdgcn_cvt_pkrtz(f[6], f[7]); r[6] = (_Float16)p.x; r[7] = (_Float16)p.y;
#else
#pragma unroll
    for (int j = 0; j < 8; ++j) r[j] = (_Float16)f[j];
#endif
    return r;
}

// One (node,col) activation: (1-sigmoid(az))*tanh(ah), relu, * W_lin.
// az/ah arrive pre-scaled by log2e / 2*log2e so raw exp2 works.
// v = (e2-1) / ((1+e1)*(e2+1)); clamp keeps e2 finite (avoids inf*0 NaN).
__device__ __forceinline__ float gate_term(float az, float ah, float wl, float osum)
{
    const float e1 = EXP2(az);
    const float e2 = EXP2(fminf(ah, 126.0f));
    const float r  = __builtin_amdgcn_rcpf((1.0f + e1) * (e2 + 1.0f));
    float v = (e2 - 1.0f) * r;
    v = v > 0.0f ? v : 0.0f;
    return fmaf(v, wl, osum);
}

// Fully fused: no prep kernel, no workspace. Each wave builds its 4 B
// fragments in registers from the raw weights (addresses identical across
// blocks -> L1/L2 broadcast hits). One block = one graph (256 nodes); wave
// wv handles nodes [wv*64, wv*64+64) as 4 MFMA M-tiles of 16 nodes.
// mfma_f32_16x16x32_f16 with A=[Ah|Al] (RTZ hi + exact residual of x),
// B=[W16;W16] stacked -> D = x*W exact up to f16 weight rounding.
// A layout: lane=(q<<4)|m holds A[m][k=q*8+j]; B: quad q holds rows
// k=(q&1)*8+j; C/D: col=m, row=q*4+reg. (HW-verified layouts.)
__global__ __launch_bounds__(256, 6) void gcn_fused(
    const float* __restrict__ x,
    const float* __restrict__ Wz, const float* __restrict__ bz,
    const float* __restrict__ Wh, const float* __restrict__ bh,
    const float* __restrict__ Wlin, const float* __restrict__ blin,
    float* __restrict__ out)
{
    const int t = threadIdx.x, g = blockIdx.x;
    const int lane = t & 63, wv = t >> 6;
    const int q = lane >> 4, m = lane & 15;

    // ---- Build B fragments in registers (weights pre-scaled by log2e) ----
    half8 Bz0, Bz1, Bh0, Bh1;
    {
        const int krow = (q & 1) * 8;         // rows 0..15, duplicated q>=2
#pragma unroll
        for (int j = 0; j < 8; ++j) {
            const float* wzp = Wz + (krow + j) * 32;   // W[0,0] row; +1536 = W[1,0]
            const float* whp = Wh + (krow + j) * 32;
            Bz0[j] = (_Float16)((wzp[m]      + wzp[1536 + m])      * LOG2E);
            Bz1[j] = (_Float16)((wzp[16 + m] + wzp[1536 + 16 + m]) * LOG2E);
            Bh0[j] = (_Float16)((whp[m]      + whp[1536 + m])      * (2.0f * LOG2E));
            Bh1[j] = (_Float16)((whp[16 + m] + whp[1536 + 16 + m]) * (2.0f * LOG2E));
        }
    }
    const float bz0 = bz[m] * LOG2E,          bz1 = bz[16 + m] * LOG2E;
    const float bh0 = bh[m] * (2.0f * LOG2E), bh1 = bh[16 + m] * (2.0f * LOG2E);
    const float wl0 = Wlin[m],                wl1 = Wlin[16 + m];

    // Lane (q,m) loads features (q&1)*8..+8 of node it*16+m; quads 2,3
    // re-read quads 0,1's lines (L1 hit) and carry the exact residual.
    const float* xw = x + ((size_t)g * NPG + wv * 64 + m) * F_IN + (q & 1) * 8;
    float4 c0 = *(const float4*)(xw);
    float4 c1 = *(const float4*)(xw + 4);
    const bool lo_lane = (q >= 2);
    float osum = 0.0f;

#pragma unroll
    for (int it = 0; it < 4; ++it) {
        float4 n0 = c0, n1 = c1;
        if (it < 3) {                          // prefetch next 16-node tile
            n0 = *(const float4*)(xw + (it + 1) * 256);
            n1 = *(const float4*)(xw + (it + 1) * 256 + 4);
        }
        const float xf[8] = { c0.x, c0.y, c0.z, c0.w, c1.x, c1.y, c1.z, c1.w };

        AU hi, lo, a;
        hi.h = pack8(xf);                      // RTZ hi
        float rf[8];
#pragma unroll
        for (int j = 0; j < 8; ++j) rf[j] = xf[j] - (float)hi.h[j];
        lo.h = pack8(rf);                      // exact residual (2nd rounding ~2^-22)
        a.u.x = lo_lane ? lo.u.x : hi.u.x;     // 4 cndmask on packed dwords
        a.u.y = lo_lane ? lo.u.y : hi.u.y;
        a.u.z = lo_lane ? lo.u.z : hi.u.z;
        a.u.w = lo_lane ? lo.u.w : hi.u.w;
        const half8 A = a.h;

        float4v az0 = { bz0, bz0, bz0, bz0 };
        float4v az1 = { bz1, bz1, bz1, bz1 };
        float4v ah0 = { bh0, bh0, bh0, bh0 };
        float4v ah1 = { bh1, bh1, bh1, bh1 };
        az0 = __builtin_amdgcn_mfma_f32_16x16x32_f16(A, Bz0, az0, 0, 0, 0);
        ah0 = __builtin_amdgcn_mfma_f32_16x16x32_f16(A, Bh0, ah0, 0, 0, 0);
        az1 = __builtin_amdgcn_mfma_f32_16x16x32_f16(A, Bz1, az1, 0, 0, 0);
        ah1 = __builtin_amdgcn_mfma_f32_16x16x32_f16(A, Bh1, ah1, 0, 0, 0);

#pragma unroll
        for (int i = 0; i < 4; ++i) {
            osum = gate_term(az0[i], ah0[i], wl0, osum);
            osum = gate_term(az1[i], ah1[i], wl1, osum);
        }
        c0 = n0; c1 = n1;
    }

    // Wave butterfly, then 4 partials via LDS.
#pragma unroll
    for (int off = 32; off > 0; off >>= 1)
        osum += __shfl_down(osum, off, 64);
    __shared__ float part[4];
    if (lane == 0) part[wv] = osum;
    __syncthreads();
    if (t == 0)
        out[g] = (part[0] + part[1] + part[2] + part[3]) * (1.0f / (float)NPG)
               + blin[0];
}

extern "C" void kernel_launch(void* const* d_in, const int* in_sizes, int n_in,
                              void* d_out, int out_size, void* d_ws, size_t ws_size,
                              hipStream_t stream)
{
    // 0:x 1:edge_index 2:edge_weight 3:batch 4:W_z 5:b_z 6:W_r 7:b_r 8:W_h 9:b_h 10:W_lin 11:b_lin
    const float* x    = (const float*)d_in[0];
    const float* Wz   = (const float*)d_in[4];
    const float* bz   = (const float*)d_in[5];
    const float* Wh   = (const float*)d_in[8];
    const float* bh   = (const float*)d_in[9];
    const float* Wlin = (const float*)d_in[10];
    const float* blin = (const float*)d_in[11];
    float* out = (float*)d_out;

    gcn_fused<<<N_GRAPHS, NPG, 0, stream>>>(x, Wz, bz, Wh, bh, Wlin, blin, out);
}

// Round 7
// 172.041 us; speedup vs baseline: 1.0503x; 1.0503x over previous
//
#include <hip/hip_runtime.h>

// Problem constants (from reference)
#define N_GRAPHS  4096
#define NPG       256      // nodes per graph (contiguous batch segments)
#define F_IN      16
#define HID       32
#define LOG2E     1.4426950408889634f

// d_ws layout:
//  bytes [0 .. 4095]  : 4 pre-packed f16 B fragments in MFMA lane layout.
//                       frag f (0=Z cols0-15, 1=Z cols16-31, 2=H cols0-15,
//                       3=H cols16-31), lane l: 16 bytes at f*1024 + l*16.
//                       Weights pre-scaled: Z by log2e, H by 2*log2e.
//  floats [1024..1055]: bz * log2e
//  floats [1056..1087]: bh * 2*log2e
//  floats [1088..1119]: W_lin
//  float  [1120]      : b_lin
#define WS_FLOATS 1121

typedef _Float16 half8   __attribute__((ext_vector_type(8)));  // 4 VGPR MFMA A/B
typedef __fp16   fp16x2  __attribute__((ext_vector_type(2)));  // cvt_pkrtz ret
typedef float    float4v __attribute__((ext_vector_type(4)));  // MFMA C/D

#if __has_builtin(__builtin_amdgcn_exp2f)
#define EXP2(x) __builtin_amdgcn_exp2f(x)
#else
#define EXP2(x) exp2f(x)
#endif

union AU { uint4 u; half8 h; };

// Pack 8 f32 -> 8 f16 with v_cvt_pkrtz (2 elems/inst, RTZ; residual compensates).
__device__ __forceinline__ half8 pack8(const float f[8]) {
    half8 r;
#if __has_builtin(__builtin_amdgcn_cvt_pkrtz)
    fp16x2 p;
    p = __builtin_amdgcn_cvt_pkrtz(f[0], f[1]); r[0] = (_Float16)p.x; r[1] = (_Float16)p.y;
    p = __builtin_amdgcn_cvt_pkrtz(f[2], f[3]); r[2] = (_Float16)p.x; r[3] = (_Float16)p.y;
    p = __builtin_amdgcn_cvt_pkrtz(f[4], f[5]); r[4] = (_Float16)p.x; r[5] = (_Float16)p.y;
    p = __builtin_amdgcn_cvt_pkrtz(f[6], f[7]); r[6] = (_Float16)p.x; r[7] = (_Float16)p.y;
#else
#pragma unroll
    for (int j = 0; j < 8; ++j) r[j] = (_Float16)f[j];
#endif
    return r;
}

// B fragment for lane l (q=l>>4, m=l&15) of frag f. Stacked B=[W16;W16] pairs
// with A=[Ah|Al] (K=32): quad q holds rows k=(q&1)*8+j. Weight element [r][c]
// at r*32+c; W[1,0] at +1536. (_Float16) cast = RTNE, good for weights.
__device__ __forceinline__ uint4 make_frag(int f, int l,
    const float* __restrict__ Wz, const float* __restrict__ Wh)
{
    const int q = l >> 4, m = l & 15;
    const int c = (f & 1) * 16 + m;
    const float s = (f < 2) ? LOG2E : 2.0f * LOG2E;
    const float* W = (f < 2) ? Wz : Wh;
    AU u;
#pragma unroll
    for (int j = 0; j < 8; ++j) {
        const int k = (q & 1) * 8 + j;
        u.h[j] = (_Float16)((W[k * 32 + c] + W[1536 + k * 32 + c]) * s);
    }
    return u.u;
}

__global__ __launch_bounds__(256) void prep_kernel(
    const float* __restrict__ Wz, const float* __restrict__ bz,
    const float* __restrict__ Wh, const float* __restrict__ bh,
    const float* __restrict__ Wlin, const float* __restrict__ blin,
    float* __restrict__ w)
{
    const int t = threadIdx.x;                       // 256 threads, 1 block
    ((uint4*)w)[t] = make_frag(t >> 6, t & 63, Wz, Wh);
    if (t < HID) {
        w[1024 + t] = bz[t] * LOG2E;
        w[1056 + t] = bh[t] * (2.0f * LOG2E);
        w[1088 + t] = Wlin[t];
    }
    if (t == 0) w[1120] = blin[0];
}

// One (node,col) activation: (1-sigmoid(az))*tanh(ah), relu, * W_lin.
// az/ah arrive pre-scaled by log2e / 2*log2e so raw exp2 works.
// v = (e2-1) / ((1+e1)*(e2+1)); clamp keeps e2 finite (avoids inf*0 NaN).
__device__ __forceinline__ float gate_term(float az, float ah, float wl, float osum)
{
    const float e1 = EXP2(az);
    const float e2 = EXP2(fminf(ah, 126.0f));
    const float r  = __builtin_amdgcn_rcpf((1.0f + e1) * (e2 + 1.0f));
    float v = (e2 - 1.0f) * r;
    v = v > 0.0f ? v : 0.0f;
    return fmaf(v, wl, osum);
}

// One block = one graph. Wave wv: nodes [wv*64, wv*64+64) as 4 MFMA tiles of
// 16 nodes. mfma_f32_16x16x32_f16, A=[Ah|Al] (RTZ hi + exact residual of x),
// B=[W16;W16] -> D = x*W exact up to f16 weight rounding. One MFMA per acc.
// A layout: lane=(q<<4)|m holds A[m][k=q*8+j]; C/D: col=m, row=q*4+reg.
__device__ __forceinline__ void gcn_body(const float* __restrict__ x,
                                         const float* __restrict__ w,
                                         float* __restrict__ out, int g, int t)
{
    const int lane = t & 63, wv = t >> 6;
    const int q = lane >> 4, m = lane & 15;

    // B fragments: 4 coalesced 16B loads, already packed in MFMA layout.
    const uint4* bq = (const uint4*)w;
    AU u0, u1, u2, u3;
    u0.u = bq[lane];       u1.u = bq[64 + lane];
    u2.u = bq[128 + lane]; u3.u = bq[192 + lane];
    const half8 Bz0 = u0.h, Bz1 = u1.h, Bh0 = u2.h, Bh1 = u3.h;

    const float bz0 = w[1024 + m], bz1 = w[1040 + m];
    const float bh0 = w[1056 + m], bh1 = w[1072 + m];
    const float wl0 = w[1088 + m], wl1 = w[1104 + m];

    // Lane (q,m) loads features (q&1)*8..+8 of node it*16+m; quads 2,3
    // re-read quads 0,1's lines (L1 hit) and carry the exact residual.
    const float* xw = x + ((size_t)g * NPG + wv * 64 + m) * F_IN + (q & 1) * 8;
    float4 c0 = *(const float4*)(xw);
    float4 c1 = *(const float4*)(xw + 4);
    const bool lo_lane = (q >= 2);
    float osum = 0.0f;

#pragma unroll
    for (int it = 0; it < 4; ++it) {
        float4 n0 = c0, n1 = c1;
        if (it < 3) {                          // prefetch next 16-node tile
            n0 = *(const float4*)(xw + (it + 1) * 256);
            n1 = *(const float4*)(xw + (it + 1) * 256 + 4);
        }
        const float xf[8] = { c0.x, c0.y, c0.z, c0.w, c1.x, c1.y, c1.z, c1.w };

        AU a;
        a.h = pack8(xf);                       // RTZ hi (all lanes)
        if (lo_lane) {                         // exec-masked residual re-pack
            float rf[8];
#pragma unroll
            for (int j = 0; j < 8; ++j) rf[j] = xf[j] - (float)a.h[j];
            a.h = pack8(rf);
        }
        const half8 A = a.h;

        float4v az0 = { bz0, bz0, bz0, bz0 };
        float4v az1 = { bz1, bz1, bz1, bz1 };
        float4v ah0 = { bh0, bh0, bh0, bh0 };
        float4v ah1 = { bh1, bh1, bh1, bh1 };
        az0 = __builtin_amdgcn_mfma_f32_16x16x32_f16(A, Bz0, az0, 0, 0, 0);
        ah0 = __builtin_amdgcn_mfma_f32_16x16x32_f16(A, Bh0, ah0, 0, 0, 0);
        az1 = __builtin_amdgcn_mfma_f32_16x16x32_f16(A, Bz1, az1, 0, 0, 0);
        ah1 = __builtin_amdgcn_mfma_f32_16x16x32_f16(A, Bh1, ah1, 0, 0, 0);

#pragma unroll
        for (int i = 0; i < 4; ++i) {
            osum = gate_term(az0[i], ah0[i], wl0, osum);
            osum = gate_term(az1[i], ah1[i], wl1, osum);
        }
        c0 = n0; c1 = n1;
    }

    // Wave butterfly, then 4 partials via LDS.
#pragma unroll
    for (int off = 32; off > 0; off >>= 1)
        osum += __shfl_down(osum, off, 64);
    __shared__ float part[4];
    if (lane == 0) part[wv] = osum;
    __syncthreads();
    if (t == 0)
        out[g] = (part[0] + part[1] + part[2] + part[3]) * (1.0f / (float)NPG)
               + w[1120];
}

__global__ __launch_bounds__(256) void gcn_main(
    const float* __restrict__ x, const float* __restrict__ w, float* __restrict__ out)
{
    gcn_body(x, w, out, blockIdx.x, threadIdx.x);
}

// Fallback if ws_size too small: build the same 1121-float image in LDS.
__global__ __launch_bounds__(256) void gcn_main_lds(
    const float* __restrict__ x,
    const float* __restrict__ Wz, const float* __restrict__ bz,
    const float* __restrict__ Wh, const float* __restrict__ bh,
    const float* __restrict__ Wlin, const float* __restrict__ blin,
    float* __restrict__ out)
{
    __shared__ __attribute__((aligned(16))) float w[WS_FLOATS];
    const int t = threadIdx.x;
    ((uint4*)w)[t] = make_frag(t >> 6, t & 63, Wz, Wh);
    if (t < HID) {
        w[1024 + t] = bz[t] * LOG2E;
        w[1056 + t] = bh[t] * (2.0f * LOG2E);
        w[1088 + t] = Wlin[t];
    }
    if (t == 0) w[1120] = blin[0];
    __syncthreads();
    gcn_body(x, w, out, blockIdx.x, t);
}

extern "C" void kernel_launch(void* const* d_in, const int* in_sizes, int n_in,
                              void* d_out, int out_size, void* d_ws, size_t ws_size,
                              hipStream_t stream)
{
    // 0:x 1:edge_index 2:edge_weight 3:batch 4:W_z 5:b_z 6:W_r 7:b_r 8:W_h 9:b_h 10:W_lin 11:b_lin
    const float* x    = (const float*)d_in[0];
    const float* Wz   = (const float*)d_in[4];
    const float* bz   = (const float*)d_in[5];
    const float* Wh   = (const float*)d_in[8];
    const float* bh   = (const float*)d_in[9];
    const float* Wlin = (const float*)d_in[10];
    const float* blin = (const float*)d_in[11];
    float* out = (float*)d_out;

    if (ws_size >= WS_FLOATS * sizeof(float)) {
        float* w = (float*)d_ws;
        prep_kernel<<<1, 256, 0, stream>>>(Wz, bz, Wh, bh, Wlin, blin, w);
        gcn_main<<<N_GRAPHS, NPG, 0, stream>>>(x, w, out);
    } else {
        gcn_main_lds<<<N_GRAPHS, NPG, 0, stream>>>(x, Wz, bz, Wh, bh, Wlin, blin, out);
    }
}